// Round 2
// baseline (21288.461 us; speedup 1.0000x reference)
//
#include <hip/hip_runtime.h>

#define NN 100000
#define NE 800000
#define NL 200000
#define HEADS 4

// ---------------- tiled register-blocked GEMM -------------------------------
// C[r,j] = act(sum_k A[r,k]*B[k,j] + bias[j]); A row-major [n_rows,K], B [K,ncols].
// Whole K fits in LDS (K<=96). BM x BN block tile, TM x TN per-thread micro-tile.
template<int K, int BM, int BN, int TM, int TN, bool RELU, bool BIAS>
__launch_bounds__(256)
__global__ void gemm_tiled(const float* __restrict__ A, const float* __restrict__ B,
                           const float* __restrict__ bias, float* __restrict__ C,
                           int n_rows, int ncols) {
    constexpr int TX = BN / TN;          // threads along N
    constexpr int TY = BM / TM;          // threads along M
    static_assert(TX * TY == 256, "thread tiling must cover 256");
    constexpr int PAD = 4;
    __shared__ float As[K][BM + PAD];    // A transposed: As[k][r]
    __shared__ float Bs[K][BN];

    const int row0 = blockIdx.x * BM;
    const int col0 = blockIdx.y * BN;

    for (int i = threadIdx.x; i < BM * K; i += 256) {
        int r = i / K, k = i - r * K;
        int gr = row0 + r;
        As[k][r] = (gr < n_rows) ? A[(size_t)gr * K + k] : 0.f;
    }
    for (int i = threadIdx.x; i < K * BN; i += 256) {
        int k = i / BN, j = i - k * BN;
        int gc = col0 + j;
        Bs[k][j] = (gc < ncols) ? B[(size_t)k * ncols + gc] : 0.f;
    }
    __syncthreads();

    const int tx = threadIdx.x % TX;
    const int ty = threadIdx.x / TX;
    const int tm0 = ty * TM;
    const int tn0 = tx * TN;

    float acc[TM][TN] = {};
    #pragma unroll
    for (int k = 0; k < K; ++k) {
        float a[TM], b[TN];
        if constexpr (TM == 4) {
            float4 v = *(const float4*)&As[k][tm0];
            a[0] = v.x; a[1] = v.y; a[2] = v.z; a[3] = v.w;
        } else {
            #pragma unroll
            for (int m = 0; m < TM; ++m) a[m] = As[k][tm0 + m];
        }
        if constexpr (TN == 4) {
            float4 v = *(const float4*)&Bs[k][tn0];
            b[0] = v.x; b[1] = v.y; b[2] = v.z; b[3] = v.w;
        } else if constexpr (TN == 2) {
            float2 v = *(const float2*)&Bs[k][tn0];
            b[0] = v.x; b[1] = v.y;
        } else {
            #pragma unroll
            for (int n = 0; n < TN; ++n) b[n] = Bs[k][tn0 + n];
        }
        #pragma unroll
        for (int m = 0; m < TM; ++m)
            #pragma unroll
            for (int n = 0; n < TN; ++n)
                acc[m][n] = fmaf(a[m], b[n], acc[m][n]);
    }

    #pragma unroll
    for (int m = 0; m < TM; ++m) {
        int gr = row0 + tm0 + m;
        if (gr >= n_rows) break;
        #pragma unroll
        for (int n = 0; n < TN; ++n) {
            int gc = col0 + tn0 + n;
            if (gc >= ncols) continue;
            float s = acc[m][n];
            if (BIAS) s += bias[gc];
            if (RELU) s = fmaxf(s, 0.f);
            C[(size_t)gr * ncols + gc] = s;
        }
    }
}

// ---------------- per-(node,head) attention logits --------------------------
template<int C>
__global__ void calc_alpha(const float* __restrict__ h, const float* __restrict__ a_src,
                           const float* __restrict__ a_dst, float* __restrict__ as_out,
                           float* __restrict__ ad_out) {
    int i = blockIdx.x * blockDim.x + threadIdx.x;   // n*HEADS + hd
    if (i >= NN * HEADS) return;
    int n = i / HEADS, hd = i % HEADS;
    const float* hp  = h + (size_t)n * HEADS * C + hd * C;
    const float* asp = a_src + hd * C;
    const float* adp = a_dst + hd * C;
    float s1 = 0.f, s2 = 0.f;
    #pragma unroll 8
    for (int c = 0; c < C; ++c) { float v = hp[c]; s1 += v * asp[c]; s2 += v * adp[c]; }
    as_out[i] = s1; ad_out[i] = s2;
}

__device__ __forceinline__ float lrelu02(float v) { return v > 0.f ? v : 0.2f * v; }

// ---------------- softmax denominator per (dst, head) -----------------------
__global__ void edge_denom(const int* __restrict__ src, const int* __restrict__ dst,
                           const float* __restrict__ as_, const float* __restrict__ ad_,
                           float* __restrict__ den) {
    int i = blockIdx.x * blockDim.x + threadIdx.x;   // e*HEADS + hd
    if (i >= NE * HEADS) return;
    int e = i / HEADS, hd = i % HEADS;
    int s = src[e], d = dst[e];
    float v = lrelu02(as_[s * HEADS + hd] + ad_[d * HEADS + hd]);
    atomicAdd(&den[d * HEADS + hd], __expf(v));
}

// ---------------- normalized attention weight per (edge, head) --------------
__global__ void alpha_kernel(const int* __restrict__ src, const int* __restrict__ dst,
                             const float* __restrict__ as_, const float* __restrict__ ad_,
                             const float* __restrict__ den, float* __restrict__ alpha) {
    int i = blockIdx.x * blockDim.x + threadIdx.x;   // e*HEADS + hd
    if (i >= NE * HEADS) return;
    int e = i / HEADS, hd = i % HEADS;
    int s = src[e], d = dst[e];
    float v = lrelu02(as_[s * HEADS + hd] + ad_[d * HEADS + hd]);
    alpha[i] = __expf(v) / (den[d * HEADS + hd] + 1e-16f);
}

// ---------------- weighted aggregation, heads folded ------------------------
// agg[d, c] += sum_h alpha[e,h] * h[s, h*C + c]   (mean over heads applied later)
template<int C>
__global__ void edge_agg(const int* __restrict__ src, const int* __restrict__ dst,
                         const float* __restrict__ alpha, const float* __restrict__ h,
                         float* __restrict__ agg) {
    int tid = blockIdx.x * blockDim.x + threadIdx.x;
    int e = tid / C, c = tid % C;
    if (e >= NE) return;
    int s = src[e], d = dst[e];
    float4 w = *(const float4*)&alpha[e * HEADS];
    const float* hp = h + (size_t)s * HEADS * C + c;
    float sum = w.x * hp[0] + w.y * hp[C] + w.z * hp[2 * C] + w.w * hp[3 * C];
    atomicAdd(&agg[(size_t)d * C + c], sum);
}

// ---------------- mean over heads + bias + relu ------------------------------
template<int C>
__global__ void finalize(const float* __restrict__ agg, const float* __restrict__ bias,
                         float* __restrict__ out) {
    int i = blockIdx.x * blockDim.x + threadIdx.x;   // n*C + c
    if (i >= NN * C) return;
    out[i] = fmaxf(agg[i] * 0.25f + bias[i % C], 0.f);
}

// ---------------- link decoder ----------------------------------------------
__global__ void link_kernel(const int* __restrict__ lsrc, const int* __restrict__ ldst,
                            const float* __restrict__ z, float* __restrict__ out) {
    int e = blockIdx.x * blockDim.x + threadIdx.x;
    if (e >= NL) return;
    const float4* zs = (const float4*)(z + (size_t)lsrc[e] * 32);
    const float4* zd = (const float4*)(z + (size_t)ldst[e] * 32);
    float sum = 0.f;
    #pragma unroll
    for (int i = 0; i < 8; ++i) {
        float4 a = zs[i], b = zd[i];
        sum += a.x * b.x + a.y * b.y + a.z * b.z + a.w * b.w;
    }
    out[e] = sum;
}

extern "C" void kernel_launch(void* const* d_in, const int* in_sizes, int n_in,
                              void* d_out, int out_size, void* d_ws, size_t ws_size,
                              hipStream_t stream) {
    const float* x     = (const float*)d_in[0];
    const int*   ei    = (const int*)d_in[1];
    const int*   eli   = (const int*)d_in[2];
    const float* W0    = (const float*)d_in[3];
    const float* as0   = (const float*)d_in[4];
    const float* ad0   = (const float*)d_in[5];
    const float* b0    = (const float*)d_in[6];
    const float* W1    = (const float*)d_in[7];
    const float* as1   = (const float*)d_in[8];
    const float* ad1   = (const float*)d_in[9];
    const float* b1    = (const float*)d_in[10];
    const float* lin_w = (const float*)d_in[11];
    const float* lin_b = (const float*)d_in[12];
    const float* d1_w  = (const float*)d_in[13];
    const float* d1_b  = (const float*)d_in[14];
    const float* d2_w  = (const float*)d_in[15];
    const float* d2_b  = (const float*)d_in[16];
    const float* d3_w  = (const float*)d_in[17];
    const float* d3_b  = (const float*)d_in[18];
    const float* d4_w  = (const float*)d_in[19];
    const float* d4_b  = (const float*)d_in[20];

    const int* src = ei;            // edge_index[0]
    const int* dst = ei + NE;       // edge_index[1]
    const int* ls  = eli;
    const int* ld  = eli + NL;

    float* ws = (float*)d_ws;
    // layout (floats): h [N*256] | agg [N*64] | outb [N*64] | as [N*4] | ad [N*4] | den [N*4]
    float* h_buf = ws;
    float* agg   = ws + (size_t)NN * 256;
    float* outb  = ws + (size_t)NN * 320;
    float* asb   = ws + (size_t)NN * 384;
    float* adb   = ws + (size_t)NN * 388;
    float* den   = ws + (size_t)NN * 392;
    // alpha[e][h] overlays outb (dead during the edge phase of each layer):
    // NE*4 = 3.2M floats <= NN*64 = 6.4M floats.
    float* alphab = outb;
    // decoder intermediates reuse the h region
    float* z  = h_buf;                       // [N,32]
    float* e1 = h_buf + (size_t)NN * 32;     // [N,32]
    float* e2 = h_buf + (size_t)NN * 64;     // [N,64]
    float* e3 = h_buf + (size_t)NN * 128;    // [N,96]

    float* link_out = (float*)d_out;
    float* expr_out = (float*)d_out + NL;

    const int MT = (NN + 63) / 64;           // 1563 M-tiles
    const int EH = (NE * HEADS + 255) / 256;

    // ---------------- Layer 0 (C=64 per head) ----------------
    gemm_tiled<64, 64, 64, 4, 4, false, false><<<dim3(MT, 4), 256, 0, stream>>>(x, W0, nullptr, h_buf, NN, 256);
    calc_alpha<64><<<(NN * HEADS + 255) / 256, 256, 0, stream>>>(h_buf, as0, ad0, asb, adb);
    hipMemsetAsync(den, 0, (size_t)NN * HEADS * 4, stream);
    edge_denom<<<EH, 256, 0, stream>>>(src, dst, asb, adb, den);
    alpha_kernel<<<EH, 256, 0, stream>>>(src, dst, asb, adb, den, alphab);
    hipMemsetAsync(agg, 0, (size_t)NN * 64 * 4, stream);
    edge_agg<64><<<(size_t)(NE * 64) / 256, 256, 0, stream>>>(src, dst, alphab, h_buf, agg);
    finalize<64><<<(NN * 64) / 256, 256, 0, stream>>>(agg, b0, outb);

    // ---------------- Layer 1 (C=32 per head) ----------------
    gemm_tiled<64, 64, 64, 4, 4, false, false><<<dim3(MT, 2), 256, 0, stream>>>(outb, W1, nullptr, h_buf, NN, 128);
    calc_alpha<32><<<(NN * HEADS + 255) / 256, 256, 0, stream>>>(h_buf, as1, ad1, asb, adb);
    hipMemsetAsync(den, 0, (size_t)NN * HEADS * 4, stream);
    edge_denom<<<EH, 256, 0, stream>>>(src, dst, asb, adb, den);
    alpha_kernel<<<EH, 256, 0, stream>>>(src, dst, asb, adb, den, alphab);
    hipMemsetAsync(agg, 0, (size_t)NN * 32 * 4, stream);
    edge_agg<32><<<(size_t)(NE * 32) / 256, 256, 0, stream>>>(src, dst, alphab, h_buf, agg);
    finalize<32><<<(NN * 32) / 256, 256, 0, stream>>>(agg, b1, outb);

    // ---------------- lin: z = out1 @ lin_w + lin_b ----------------
    gemm_tiled<32, 64, 32, 4, 2, false, true><<<dim3(MT, 1), 256, 0, stream>>>(outb, lin_w, lin_b, z, NN, 32);

    // ---------------- link decoder ----------------
    link_kernel<<<(NL + 255) / 256, 256, 0, stream>>>(ls, ld, z, link_out);

    // ---------------- expression decoder ----------------
    gemm_tiled<32, 64, 32, 4, 2, true, true><<<dim3(MT, 1), 256, 0, stream>>>(z,  d1_w, d1_b, e1, NN, 32);
    gemm_tiled<32, 64, 64, 4, 4, true, true><<<dim3(MT, 1), 256, 0, stream>>>(e1, d2_w, d2_b, e2, NN, 64);
    gemm_tiled<64, 64, 64, 4, 4, true, true><<<dim3(MT, 2), 256, 0, stream>>>(e2, d3_w, d3_b, e3, NN, 96);
    gemm_tiled<96, 64, 64, 4, 4, false, true><<<dim3(MT, 8), 256, 0, stream>>>(e3, d4_w, d4_b, expr_out, NN, 500);
}